// Round 3
// baseline (270.526 us; speedup 1.0000x reference)
//
#include <hip/hip_runtime.h>
#include <hip/hip_bf16.h>
#include <stdint.h>
#include <stddef.h>

#define DIM 768

typedef short short8 __attribute__((ext_vector_type(8)));
typedef float f32x4 __attribute__((ext_vector_type(4)));

__device__ inline unsigned short f2bf_rne(float f) {
    union { float f; unsigned u; } x; x.f = f;
    unsigned r = x.u + 0x7fffu + ((x.u >> 16) & 1u);
    return (unsigned short)(r >> 16);
}

__device__ inline void gload_lds16(const void* g, void* l) {
    __builtin_amdgcn_global_load_lds((const __attribute__((address_space(1))) void*)g,
                                     (__attribute__((address_space(3))) void*)l, 16, 0, 0);
}

// Kernel 1: W [K][N] fp32 -> Bt [N][K] bf16 via LDS transpose (coalesced read AND write).
__global__ __launch_bounds__(256) void convw_kernel(
    const float* __restrict__ w, unsigned short* __restrict__ Bt)
{
    __shared__ unsigned short t[64][65];
    const int k0 = blockIdx.x * 64, n0 = blockIdx.y * 64;
    const int tid = threadIdx.x;
#pragma unroll
    for (int p = 0; p < 16; ++p) {
        int e = p * 256 + tid;
        int r = e >> 6, c = e & 63;
        t[c][r] = f2bf_rne(w[(size_t)(k0 + r) * DIM + n0 + c]);
    }
    __syncthreads();
#pragma unroll
    for (int p = 0; p < 16; ++p) {
        int e = p * 256 + tid;
        int r = e >> 6, c = e & 63;
        Bt[(size_t)(n0 + r) * DIM + k0 + c] = t[r][c];
    }
}

// Kernel 2: fused gather + GEMM + conditional select, A K-resident in LDS.
// Block = 32-row m-strip. Phase 0 gathers the strip's embedding rows ONCE,
// converts fp32->bf16, stores to a chunk-XOR-swizzled LDS panel (32x768 bf16,
// 48 KB). Then 3 n-tiles of 256 cols: B (bf16, n-major) streamed per-K-step
// via global_load_lds with a source-side XOR swizzle (kills the 8-way ds_read
// bank conflict; LDS dest stays wave-uniform+lane*16). Wave tile 32m x 64n:
// 6 ds_read_b128 -> 8 MFMA per K-step. LDS total = 65536 B -> 2 blocks/CU.
__global__ __launch_bounds__(256, 2) void fused_gemm_kernel(
    const int* __restrict__ token,
    const int* __restrict__ need_mapper,
    const float* __restrict__ emb,
    const unsigned short* __restrict__ Bt,   // [768][768] bf16, n-major
    const float* __restrict__ bias,
    float* __restrict__ out)                 // [M][768] fp32
{
    __shared__ unsigned short As[32 * DIM];   // 49152 B, swizzled: slot p of row r = chunk p^(r&7)
    __shared__ unsigned short Bs[256 * 32];   // 16384 B, slot p of row n = chunk p^((n>>1)&3)

    const int tid  = threadIdx.x;
    const int wave = tid >> 6;
    const int lane = tid & 63;
    const int quad = lane >> 4;
    const int l15  = lane & 15;
    const int m0   = blockIdx.x * 32;

    // ---- Phase 0: gather 32 embedding rows -> bf16 swizzled LDS (once) ----
    // 3072 chunks of 16 B (8 bf16 <- 8 fp32 = 32 B global); 12 iters * 256 thr.
#pragma unroll
    for (int it = 0; it < 12; ++it) {
        int e = it * 256 + tid;
        int r = e / 96;
        int q = e - r * 96;
        int p = (q & ~7) | ((q & 7) ^ (r & 7));
        int tok = token[m0 + r];
        const float* src = emb + (size_t)tok * DIM + q * 8;
        float4 v0 = *(const float4*)src;
        float4 v1 = *(const float4*)(src + 4);
        unsigned u0 = __float_as_uint(v0.x) + 0x8000u;
        unsigned u1 = __float_as_uint(v0.y) + 0x8000u;
        unsigned u2 = __float_as_uint(v0.z) + 0x8000u;
        unsigned u3 = __float_as_uint(v0.w) + 0x8000u;
        unsigned u4 = __float_as_uint(v1.x) + 0x8000u;
        unsigned u5 = __float_as_uint(v1.y) + 0x8000u;
        unsigned u6 = __float_as_uint(v1.z) + 0x8000u;
        unsigned u7 = __float_as_uint(v1.w) + 0x8000u;
        union { int i4[4]; short8 s; } pk;
        pk.i4[0] = __builtin_amdgcn_perm(u1, u0, 0x07060302);
        pk.i4[1] = __builtin_amdgcn_perm(u3, u2, 0x07060302);
        pk.i4[2] = __builtin_amdgcn_perm(u5, u4, 0x07060302);
        pk.i4[3] = __builtin_amdgcn_perm(u7, u6, 0x07060302);
        *(short8*)(As + r * DIM + p * 8) = pk.s;
    }

    // Per-thread epilogue row metadata (rows fixed across n-tiles).
    int tokr[2][4], flg[2][4];
#pragma unroll
    for (int i = 0; i < 2; ++i)
#pragma unroll
        for (int r2 = 0; r2 < 4; ++r2) {
            int row = i * 16 + quad * 4 + r2;
            int t = token[m0 + row];
            tokr[i][r2] = t;
            flg[i][r2]  = need_mapper[t];
        }

    // ---- n-tile loop: 3 x 256 cols ----
    for (int n0 = 0; n0 < DIM; n0 += 256) {
        f32x4 acc[2][4] = {};

        for (int kk = 0; kk < DIM; kk += 32) {
            __syncthreads();
            // Stage B tile [256 n][32 k] with source-side chunk swizzle.
#pragma unroll
            for (int j = 0; j < 4; ++j) {
                int nloc = (tid >> 2) + 64 * j;
                int q = (tid & 3) ^ ((nloc >> 1) & 3);
                gload_lds16(Bt + (size_t)(n0 + nloc) * DIM + kk + q * 8,
                            (char*)Bs + wave * 1024 + j * 4096);
            }
            __syncthreads();

            short8 af[2], bf[4];
#pragma unroll
            for (int i = 0; i < 2; ++i) {
                int r = i * 16 + l15;
                int q = (kk >> 3) + quad;
                int p = q ^ (r & 7);
                af[i] = *(const short8*)(As + r * DIM + p * 8);
            }
#pragma unroll
            for (int j = 0; j < 4; ++j) {
                int nl = wave * 64 + j * 16 + l15;
                int p = quad ^ ((nl >> 1) & 3);
                bf[j] = *(const short8*)(Bs + nl * 32 + p * 8);
            }
#pragma unroll
            for (int i = 0; i < 2; ++i)
#pragma unroll
                for (int j = 0; j < 4; ++j)
                    acc[i][j] = __builtin_amdgcn_mfma_f32_16x16x32_bf16(af[i], bf[j], acc[i][j], 0, 0, 0);
        }

        // Epilogue for this n-tile. C/D layout: col = lane&15, row = quad*4+reg.
        const int colg = n0 + wave * 64 + l15;
        float bv[4];
#pragma unroll
        for (int j = 0; j < 4; ++j) bv[j] = bias[colg + j * 16];

#pragma unroll
        for (int i = 0; i < 2; ++i) {
#pragma unroll
            for (int r2 = 0; r2 < 4; ++r2) {
                int gm = m0 + i * 16 + quad * 4 + r2;
                float* orow = out + (size_t)gm * DIM + colg;
                if (flg[i][r2]) {
#pragma unroll
                    for (int j = 0; j < 4; ++j)
                        orow[j * 16] = acc[i][j][r2] + bv[j];
                } else {
                    const float* erow = emb + (size_t)tokr[i][r2] * DIM + colg;
#pragma unroll
                    for (int j = 0; j < 4; ++j)
                        orow[j * 16] = erow[j * 16];
                }
            }
        }
    }
}

extern "C" void kernel_launch(void* const* d_in, const int* in_sizes, int n_in,
                              void* d_out, int out_size, void* d_ws, size_t ws_size,
                              hipStream_t stream)
{
    const int*   token       = (const int*)d_in[0];
    const int*   need_mapper = (const int*)d_in[1];
    const float* emb         = (const float*)d_in[2];
    const float* w           = (const float*)d_in[3];
    const float* bias        = (const float*)d_in[4];
    float* out = (float*)d_out;

    const int ntok = in_sizes[0];   // 32*512 = 16384

    unsigned short* Bt = (unsigned short*)d_ws;   // 768*768 bf16 = 1.18 MB

    convw_kernel<<<dim3(DIM / 64, DIM / 64), dim3(256), 0, stream>>>(w, Bt);
    fused_gemm_kernel<<<dim3(ntok / 32), dim3(256), 0, stream>>>(
        token, need_mapper, emb, Bt, bias, out);
}

// Round 4
// 252.474 us; speedup vs baseline: 1.0715x; 1.0715x over previous
//
#include <hip/hip_runtime.h>
#include <hip/hip_bf16.h>
#include <stdint.h>
#include <stddef.h>

#define DIM 768

typedef short short8 __attribute__((ext_vector_type(8)));
typedef float f32x4 __attribute__((ext_vector_type(4)));

__device__ inline unsigned short f2bf_rne(float f) {
    union { float f; unsigned u; } x; x.f = f;
    unsigned r = x.u + 0x7fffu + ((x.u >> 16) & 1u);
    return (unsigned short)(r >> 16);
}

__device__ inline void gload_lds16(const void* g, void* l) {
    __builtin_amdgcn_global_load_lds((const __attribute__((address_space(1))) void*)g,
                                     (__attribute__((address_space(3))) void*)l, 16, 0, 0);
}

// Prep kernel: blocks [0,144) transpose W -> Bt (bf16, n-major) via LDS;
// blocks [144, 144+6144) gather embedding rows ONCE: write bf16 A panel (plain
// row-major; the GEMM applies its swizzle at load time), write need==0 rows
// straight to out (fp32), record per-row flags.
#define NWBLK 144
__global__ __launch_bounds__(256) void prep_kernel(
    const int* __restrict__ token,
    const int* __restrict__ need_mapper,
    const float* __restrict__ emb,
    const float* __restrict__ w,
    float* __restrict__ out,
    unsigned short* __restrict__ Abf,
    unsigned short* __restrict__ Bt,
    int* __restrict__ flags)
{
    const int tid = threadIdx.x;
    if (blockIdx.x < NWBLK) {
        __shared__ unsigned short t[64][65];
        const int k0 = (blockIdx.x / 12) * 64, n0 = (blockIdx.x % 12) * 64;
#pragma unroll
        for (int p = 0; p < 16; ++p) {
            int e = p * 256 + tid;
            int r = e >> 6, c = e & 63;
            t[c][r] = f2bf_rne(w[(size_t)(k0 + r) * DIM + n0 + c]);
        }
        __syncthreads();
#pragma unroll
        for (int p = 0; p < 16; ++p) {
            int e = p * 256 + tid;
            int r = e >> 6, c = e & 63;
            Bt[(size_t)(n0 + r) * DIM + k0 + c] = t[r][c];
        }
        return;
    }
    // Gather: one 8-float chunk per thread. 16384 rows x 96 chunks.
    int e = (blockIdx.x - NWBLK) * 256 + tid;
    int r = e / 96;
    int q = e - r * 96;
    int tok = token[r];
    int need = need_mapper[tok];
    const float* src = emb + (size_t)tok * DIM + q * 8;
    float4 v0 = *(const float4*)src;
    float4 v1 = *(const float4*)(src + 4);
    unsigned u0 = __float_as_uint(v0.x) + 0x8000u;
    unsigned u1 = __float_as_uint(v0.y) + 0x8000u;
    unsigned u2 = __float_as_uint(v0.z) + 0x8000u;
    unsigned u3 = __float_as_uint(v0.w) + 0x8000u;
    unsigned u4 = __float_as_uint(v1.x) + 0x8000u;
    unsigned u5 = __float_as_uint(v1.y) + 0x8000u;
    unsigned u6 = __float_as_uint(v1.z) + 0x8000u;
    unsigned u7 = __float_as_uint(v1.w) + 0x8000u;
    union { int i4[4]; short8 s; } pk;
    pk.i4[0] = __builtin_amdgcn_perm(u1, u0, 0x07060302);
    pk.i4[1] = __builtin_amdgcn_perm(u3, u2, 0x07060302);
    pk.i4[2] = __builtin_amdgcn_perm(u5, u4, 0x07060302);
    pk.i4[3] = __builtin_amdgcn_perm(u7, u6, 0x07060302);
    *(short8*)(Abf + (size_t)r * DIM + q * 8) = pk.s;
    if (!need) {
        float* dst = out + (size_t)r * DIM + q * 8;
        *(float4*)dst = v0;
        *(float4*)(dst + 4) = v1;
    }
    if (q == 0) flags[r] = need;
}

// GEMM: C[m][n] = sum_k A[m][k]*Bt[n][k] + bias[n], written only where flags[m].
// m97 structure: 128x128 tile, BK=32, 4 waves, 4x4 16x16x32 bf16 MFMA/wave.
// XOR chunk swizzle baked into the per-lane GLOBAL source address of
// global_load_lds (dest stays wave-uniform + lane*16); fragment slot is the
// lane-constant quad ^ ((l15>>1)&3) -> 2-way LDS banking (free).
__global__ __launch_bounds__(256) void gemm_kernel(
    const unsigned short* __restrict__ A,    // [M][768] bf16
    const unsigned short* __restrict__ Bt,   // [768][768] bf16, n-major
    const float* __restrict__ bias,
    const int* __restrict__ flags,
    float* __restrict__ out)
{
    __shared__ unsigned short As[128 * 32];
    __shared__ unsigned short Bs[128 * 32];

    const int tid  = threadIdx.x;
    const int wave = tid >> 6;
    const int lane = tid & 63;
    const int quad = lane >> 4;
    const int l15  = lane & 15;
    const int wm   = wave >> 1;
    const int wn   = wave & 1;
    const int tile_n = blockIdx.x;   // fastest: the 6 sharers of an m-tile are adjacent
    const int tile_m = blockIdx.y;

    const int srow = tid >> 2;                              // 0..63
    const int schk = (tid & 3) ^ ((srow >> 1) & 3);         // swizzled source chunk
    const unsigned short* Ag = A  + (size_t)(tile_m * 128 + srow) * DIM + schk * 8;
    const unsigned short* Bg = Bt + (size_t)(tile_n * 128 + srow) * DIM + schk * 8;

    unsigned short* AsW = As + wave * 512;                  // wave-uniform LDS bases
    unsigned short* BsW = Bs + wave * 512;

    const int slot = quad ^ ((l15 >> 1) & 3);               // fragment chunk slot

    f32x4 acc[4][4] = {};

    for (int kk = 0; kk < DIM; kk += 32) {
        __syncthreads();
        gload_lds16(Ag + kk,            AsW);
        gload_lds16(Ag + kk + 64 * DIM, AsW + 2048);
        gload_lds16(Bg + kk,            BsW);
        gload_lds16(Bg + kk + 64 * DIM, BsW + 2048);
        __syncthreads();

        short8 af[4], bf[4];
#pragma unroll
        for (int i = 0; i < 4; ++i)
            af[i] = *(const short8*)(As + (wm * 64 + i * 16 + l15) * 32 + slot * 8);
#pragma unroll
        for (int j = 0; j < 4; ++j)
            bf[j] = *(const short8*)(Bs + (wn * 64 + j * 16 + l15) * 32 + slot * 8);
#pragma unroll
        for (int i = 0; i < 4; ++i)
#pragma unroll
            for (int j = 0; j < 4; ++j)
                acc[i][j] = __builtin_amdgcn_mfma_f32_16x16x32_bf16(af[i], bf[j], acc[i][j], 0, 0, 0);
    }

    // Epilogue. C/D layout: col = lane&15, row = quad*4 + reg.
    const int colg = tile_n * 128 + wn * 64 + l15;
    float bv[4];
#pragma unroll
    for (int j = 0; j < 4; ++j) bv[j] = bias[colg + j * 16];

    const int row0 = tile_m * 128 + wm * 64 + quad * 4;
#pragma unroll
    for (int i = 0; i < 4; ++i) {
#pragma unroll
        for (int r = 0; r < 4; ++r) {
            int gm = row0 + i * 16 + r;
            if (flags[gm] != 0) {
                float* orow = out + (size_t)gm * DIM + colg;
#pragma unroll
                for (int j = 0; j < 4; ++j)
                    orow[j * 16] = acc[i][j][r] + bv[j];
            }
        }
    }
}

extern "C" void kernel_launch(void* const* d_in, const int* in_sizes, int n_in,
                              void* d_out, int out_size, void* d_ws, size_t ws_size,
                              hipStream_t stream)
{
    const int*   token       = (const int*)d_in[0];
    const int*   need_mapper = (const int*)d_in[1];
    const float* emb         = (const float*)d_in[2];
    const float* w           = (const float*)d_in[3];
    const float* bias        = (const float*)d_in[4];
    float* out = (float*)d_out;

    const int ntok = in_sizes[0];   // 32*512 = 16384

    unsigned short* Abf = (unsigned short*)d_ws;                                   // 25.2 MB
    unsigned short* Bt  = (unsigned short*)((char*)d_ws + (size_t)ntok * DIM * 2); // 1.18 MB
    int* flags = (int*)((char*)d_ws + (size_t)ntok * DIM * 2 + (size_t)DIM * DIM * 2);

    int gblocks = NWBLK + (ntok * (DIM / 8)) / 256;   // 144 + 6144
    prep_kernel<<<dim3(gblocks), dim3(256), 0, stream>>>(
        token, need_mapper, emb, w, out, Abf, Bt, flags);
    gemm_kernel<<<dim3(DIM / 128, ntok / 128), dim3(256), 0, stream>>>(
        Abf, Bt, bias, flags, out);
}

// Round 5
// 245.237 us; speedup vs baseline: 1.1031x; 1.0295x over previous
//
#include <hip/hip_runtime.h>
#include <hip/hip_bf16.h>
#include <stdint.h>
#include <stddef.h>

#define DIM 768

typedef short short8 __attribute__((ext_vector_type(8)));
typedef float f32x4 __attribute__((ext_vector_type(4)));

__device__ inline unsigned short f2bf_rne(float f) {
    union { float f; unsigned u; } x; x.f = f;
    unsigned r = x.u + 0x7fffu + ((x.u >> 16) & 1u);
    return (unsigned short)(r >> 16);
}

__device__ inline void gload_lds16(const void* g, void* l) {
    __builtin_amdgcn_global_load_lds((const __attribute__((address_space(1))) void*)g,
                                     (__attribute__((address_space(3))) void*)l, 16, 0, 0);
}

// Prep kernel, 1024 threads/block.
//  Blocks [0, ntok/16): wave-per-row gather + compaction.
//    need==0 -> fp32 row straight to out. need==1 -> bf16 row appended to
//    compacted Acmp at pos from a block-aggregated atomicAdd; rowmap[pos]=row.
//  Blocks [ntok/16, +144): W [K][N] fp32 -> Bt [N][K] bf16 via LDS transpose.
__global__ __launch_bounds__(1024) void prep_kernel(
    const int* __restrict__ token,
    const int* __restrict__ need_mapper,
    const float* __restrict__ emb,
    const float* __restrict__ w,
    float* __restrict__ out,
    unsigned short* __restrict__ Acmp,
    unsigned short* __restrict__ Bt,
    int* __restrict__ rowmap,
    int* __restrict__ cnt,
    int nGatherBlk)
{
    const int tid = threadIdx.x;
    if ((int)blockIdx.x < nGatherBlk) {
        __shared__ int sneed[16], soffs[16], sbase;
        const int wave = tid >> 6, lane = tid & 63;
        const int r = blockIdx.x * 16 + wave;
        const int tok = token[r];
        const int need = need_mapper[tok];
        if (lane == 0) sneed[wave] = need;

        // Load the row while the compaction scan happens.
        const float* src = emb + (size_t)tok * DIM;
        float4 v[3];
#pragma unroll
        for (int j = 0; j < 3; ++j)
            v[j] = *(const float4*)(src + (j * 64 + lane) * 4);

        __syncthreads();
        if (tid == 0) {
            int tot = 0;
#pragma unroll
            for (int i = 0; i < 16; ++i) { soffs[i] = tot; tot += sneed[i]; }
            sbase = atomicAdd(cnt, tot);
        }
        __syncthreads();

        if (need) {
            const int pos = sbase + soffs[wave];
            if (lane == 0) rowmap[pos] = r;
            unsigned short* arow = Acmp + (size_t)pos * DIM;
#pragma unroll
            for (int j = 0; j < 3; ++j) {
                ushort4 h;
                h.x = f2bf_rne(v[j].x); h.y = f2bf_rne(v[j].y);
                h.z = f2bf_rne(v[j].z); h.w = f2bf_rne(v[j].w);
                *(ushort4*)(arow + (j * 64 + lane) * 4) = h;
            }
        } else {
            float* drow = out + (size_t)r * DIM;
#pragma unroll
            for (int j = 0; j < 3; ++j)
                *(float4*)(drow + (j * 64 + lane) * 4) = v[j];
        }
        return;
    }

    // ---- W transpose path ----
    __shared__ unsigned short t[64][65];
    const int b = blockIdx.x - nGatherBlk;        // 0..143
    const int k0 = (b / 12) * 64, n0 = (b % 12) * 64;
#pragma unroll
    for (int p = 0; p < 4; ++p) {
        int e = p * 1024 + tid;
        int r = e >> 6, c = e & 63;
        t[c][r] = f2bf_rne(w[(size_t)(k0 + r) * DIM + n0 + c]);
    }
    __syncthreads();
#pragma unroll
    for (int p = 0; p < 4; ++p) {
        int e = p * 1024 + tid;
        int r = e >> 6, c = e & 63;
        Bt[(size_t)(n0 + r) * DIM + k0 + c] = t[r][c];
    }
}

// GEMM on compacted rows: C[m][n] = sum_k Acmp[m][k]*Bt[n][k] + bias[n],
// scattered to out via rowmap. m97 structure: 128x128 tile, BK=32, 4 waves,
// 4x4 16x16x32 bf16 MFMA per wave. Blocks beyond the compacted row count
// (read from ws) exit immediately; tail-tile A reads hit 0xAA poison
// (+-3e-13 bf16, harmless) and their stores are guarded by gm < Mp.
__global__ __launch_bounds__(256) void gemm_kernel(
    const unsigned short* __restrict__ A,    // [Mp][768] bf16, compacted
    const unsigned short* __restrict__ Bt,   // [768][768] bf16, n-major
    const float* __restrict__ bias,
    const int* __restrict__ rowmap,
    const int* __restrict__ cnt,
    float* __restrict__ out)
{
    const int Mp = *cnt;
    const int tile_n = blockIdx.x;
    const int tile_m = blockIdx.y;
    if (tile_m * 128 >= Mp) return;

    __shared__ unsigned short As[128 * 32];
    __shared__ unsigned short Bs[128 * 32];

    const int tid  = threadIdx.x;
    const int wave = tid >> 6;
    const int lane = tid & 63;
    const int quad = lane >> 4;
    const int l15  = lane & 15;
    const int wm   = wave >> 1;
    const int wn   = wave & 1;

    const int srow = tid >> 2;
    const int schk = (tid & 3) * 8;
    const unsigned short* Ag = A  + (size_t)(tile_m * 128 + srow) * DIM + schk;
    const unsigned short* Bg = Bt + (size_t)(tile_n * 128 + srow) * DIM + schk;

    unsigned short* AsW = As + wave * 512;
    unsigned short* BsW = Bs + wave * 512;

    f32x4 acc[4][4] = {};

    for (int kk = 0; kk < DIM; kk += 32) {
        __syncthreads();
        gload_lds16(Ag + kk,            AsW);
        gload_lds16(Ag + kk + 64 * DIM, AsW + 2048);
        gload_lds16(Bg + kk,            BsW);
        gload_lds16(Bg + kk + 64 * DIM, BsW + 2048);
        __syncthreads();

        short8 af[4], bf[4];
#pragma unroll
        for (int i = 0; i < 4; ++i)
            af[i] = *(const short8*)(As + (wm * 64 + i * 16 + l15) * 32 + quad * 8);
#pragma unroll
        for (int j = 0; j < 4; ++j)
            bf[j] = *(const short8*)(Bs + (wn * 64 + j * 16 + l15) * 32 + quad * 8);
#pragma unroll
        for (int i = 0; i < 4; ++i)
#pragma unroll
            for (int j = 0; j < 4; ++j)
                acc[i][j] = __builtin_amdgcn_mfma_f32_16x16x32_bf16(af[i], bf[j], acc[i][j], 0, 0, 0);
    }

    // Epilogue. C/D layout: col = lane&15, row = quad*4 + reg.
    const int colg = tile_n * 128 + wn * 64 + l15;
    float bv[4];
#pragma unroll
    for (int j = 0; j < 4; ++j) bv[j] = bias[colg + j * 16];

    const int row0 = tile_m * 128 + wm * 64 + quad * 4;
#pragma unroll
    for (int i = 0; i < 4; ++i) {
#pragma unroll
        for (int r = 0; r < 4; ++r) {
            int gm = row0 + i * 16 + r;
            if (gm < Mp) {
                float* orow = out + (size_t)rowmap[gm] * DIM + colg;
#pragma unroll
                for (int j = 0; j < 4; ++j)
                    orow[j * 16] = acc[i][j][r] + bv[j];
            }
        }
    }
}

extern "C" void kernel_launch(void* const* d_in, const int* in_sizes, int n_in,
                              void* d_out, int out_size, void* d_ws, size_t ws_size,
                              hipStream_t stream)
{
    const int*   token       = (const int*)d_in[0];
    const int*   need_mapper = (const int*)d_in[1];
    const float* emb         = (const float*)d_in[2];
    const float* w           = (const float*)d_in[3];
    const float* bias        = (const float*)d_in[4];
    float* out = (float*)d_out;

    const int ntok = in_sizes[0];   // 32*512 = 16384

    const size_t ACMP_B  = (size_t)ntok * DIM * 2;        // 25.2 MB (upper bound)
    const size_t BT_B    = (size_t)DIM * DIM * 2;         // 1.18 MB
    unsigned short* Acmp = (unsigned short*)d_ws;
    unsigned short* Bt   = (unsigned short*)((char*)d_ws + ACMP_B);
    int* rowmap          = (int*)((char*)d_ws + ACMP_B + BT_B);
    int* cnt             = (int*)((char*)d_ws + ACMP_B + BT_B + (size_t)ntok * 4);

    hipMemsetAsync(cnt, 0, 4, stream);

    const int nGatherBlk = ntok / 16;                     // 1024
    prep_kernel<<<dim3(nGatherBlk + 144), dim3(1024), 0, stream>>>(
        token, need_mapper, emb, w, out, Acmp, Bt, rowmap, cnt, nGatherBlk);
    gemm_kernel<<<dim3(DIM / 128, ntok / 128), dim3(256), 0, stream>>>(
        Acmp, Bt, bias, rowmap, cnt, out);
}